// Round 1
// baseline (944.336 us; speedup 1.0000x reference)
//
#include <hip/hip_runtime.h>
#include <hip/hip_bf16.h>
#include <math.h>

#define NODES 50000
#define NEDGE 800000
#define NT_TILES 782        // 64-row tiles
#define NBUCK 391           // buckets of 128 nodes (391*128 = 50048)
#define BSHIFT 7
#define BCAP 2560           // bucket capacity (avg 2046, ~+11 sigma margin)
#define NP1 195             // pass-1 blocks
#define EPB1 4104           // edges per pass-1 block (195*4104 >= 800000)

typedef __bf16 bf16_t;
typedef __bf16 bf16x8 __attribute__((ext_vector_type(8)));
typedef float floatx4 __attribute__((ext_vector_type(4)));

__device__ __forceinline__ float bfbits2f(unsigned int hi16) {
    union { unsigned int u; float f; } c; c.u = hi16; return c.f;
}
__device__ __forceinline__ unsigned short f2bfbits(float f) {
    bf16_t b = (bf16_t)f; unsigned short u;
    __builtin_memcpy(&u, &b, 2); return u;
}

// act: 0=none, 1=relu, 2=gelu(tanh-approx, fast exp), 3=softplus(fast)
__device__ __forceinline__ float act_rt(float v, int act) {
    if (act == 1) return fmaxf(v, 0.f);
    if (act == 2) {
        float w = 0.79788456f * (v + 0.044715f * v * v * v);
        float e = __expf(2.f * w);
        float th = 1.f - 2.f / (e + 1.f);
        return 0.5f * v * (1.f + th);
    }
    if (act == 3) return fmaxf(v, 0.f) + __logf(1.f + __expf(-fabsf(v)));
    return v;
}

// ---------------------------------------------------------------------------
// prep: blocks 0..8 transpose weights fp32->bf16; block 9 zeroes gcur
// ---------------------------------------------------------------------------
__global__ __launch_bounds__(256) void prep_w_zero(
    const float* __restrict__ w0, const float* __restrict__ w1,
    const float* __restrict__ w2, const float* __restrict__ w3,
    const float* __restrict__ w4, const float* __restrict__ w5,
    const float* __restrict__ w6, const float* __restrict__ w7,
    const float* __restrict__ w8, bf16_t* __restrict__ wt,
    int* __restrict__ gcur)
{
    if (blockIdx.x >= 9) {
        for (int j = threadIdx.x; j < NBUCK; j += 256) gcur[j] = 0;
        return;
    }
    const float* Ws[9] = {w0, w1, w2, w3, w4, w5, w6, w7, w8};
    const float* W = Ws[blockIdx.x];
    bf16_t* o = wt + blockIdx.x * 16384;
    for (int idx = threadIdx.x; idx < 16384; idx += 256) {
        int k = idx >> 7, n = idx & 127;
        o[n * 128 + k] = (bf16_t)W[idx];
    }
}

// ---------------------------------------------------------------------------
// GEMM building blocks, 64-row tile structure.
// ---------------------------------------------------------------------------
__device__ __forceinline__ void load_w_regs(const bf16_t* __restrict__ W,
                                            uint4 (&wr)[8], int t)
{
    for (int i = 0; i < 8; ++i) {
        int c = t + i * 256;
        int row = c >> 4, g = c & 15;
        wr[i] = *(const uint4*)(W + row * 128 + g * 8);
    }
}
__device__ __forceinline__ void store_w_regs(const uint4 (&wr)[8],
                                             bf16_t* Bs, int t)
{
    for (int i = 0; i < 8; ++i) {
        int c = t + i * 256;
        int row = c >> 4, g = c & 15;
        *(uint4*)&Bs[row * 128 + ((g ^ (row & 15)) * 8)] = wr[i];
    }
}
__device__ __forceinline__ void afrag_gbf16(const bf16_t* __restrict__ A,
        bf16x8 (&af)[4], int r0, int lane, int wave, int M)
{
    int gr = r0 + wave * 16 + (lane & 15);
    gr = min(gr, M - 1);
    const bf16_t* p = A + (size_t)gr * 128 + (lane >> 4) * 8;
    for (int kc = 0; kc < 4; ++kc)
        af[kc] = *(const bf16x8*)(p + kc * 32);
}
__device__ __forceinline__ void kloop64(const bf16x8 (&af)[4], const bf16_t* Bs,
                                        floatx4 (&acc)[8], int l15, int quad)
{
    for (int ni = 0; ni < 8; ++ni)
        for (int r = 0; r < 4; ++r) acc[ni][r] = 0.f;
    for (int kc = 0; kc < 4; ++kc) {
        int kg = kc * 4 + quad;
        bf16x8 b[8];
        for (int ni = 0; ni < 8; ++ni) {
            int row = ni * 16 + l15;
            b[ni] = *(const bf16x8*)&Bs[row * 128 + ((kg ^ l15) * 8)];
        }
        for (int ni = 0; ni < 8; ++ni)
            acc[ni] = __builtin_amdgcn_mfma_f32_16x16x32_bf16(
                af[kc], b[ni], acc[ni], 0, 0, 0);
    }
}
__device__ __forceinline__ void write_Csw(bf16_t* Csw, floatx4 (&acc)[8],
        const float (&bias_r)[8], int lane, int wave, int act)
{
    const int l15 = lane & 15, quad = lane >> 4;
    for (int ni = 0; ni < 8; ++ni) {
        int col = ni * 16 + l15;
        for (int r = 0; r < 4; ++r) {
            int row = wave * 16 + quad * 4 + r;
            float v = act_rt(acc[ni][r] + bias_r[ni], act);
            Csw[row * 128 + (((col >> 3) ^ (row & 15)) << 3) + (col & 7)] = (bf16_t)v;
        }
    }
}
__device__ __forceinline__ void afrag_Csw(const bf16_t* Csw, bf16x8 (&af)[4],
                                          int lane, int wave)
{
    int l15 = lane & 15, quad = lane >> 4;
    int row = wave * 16 + l15;
    for (int kc = 0; kc < 4; ++kc) {
        int kg = kc * 4 + quad;
        af[kc] = *(const bf16x8*)&Csw[row * 128 + ((kg ^ l15) * 8)];
    }
}

// ---------------------------------------------------------------------------
// hln_p1: blocks with bid%5==4 run pass-1 edge binning (195 blocks); the rest
// run h_ln tiles (tile = bid - bid/5, 782 tiles).
// ---------------------------------------------------------------------------
__global__ __launch_bounds__(256, 3) void hln_p1(
    const float* __restrict__ x, const bf16_t* __restrict__ wt,
    const float* __restrict__ b_lin,
    const float* __restrict__ ln_g, const float* __restrict__ ln_b,
    bf16_t* __restrict__ h, bf16_t* __restrict__ xres,
    const int* __restrict__ ei, int* __restrict__ gcur,
    unsigned* __restrict__ ebuf, int M)
{
    __shared__ __align__(16) char smem[49152];
    const int t = threadIdx.x;
    const int bid = blockIdx.x;

    if (bid % 5 == 4) {
        // ---- pass 1: bin EPB1 edges into 128-node buckets ----
        int* lcnt  = (int*)smem;
        int* lbase = lcnt + NBUCK;
        for (int j = t; j < NBUCK; j += 256) lcnt[j] = 0;
        __syncthreads();
        int p1id = bid / 5;
        int base = p1id * EPB1;
        int e_end = min(base + EPB1, NEDGE);
        for (int e = base + t; e < e_end; e += 256)
            atomicAdd(&lcnt[ei[NEDGE + e] >> BSHIFT], 1);
        __syncthreads();
        for (int j = t; j < NBUCK; j += 256) {
            lbase[j] = atomicAdd(&gcur[j], lcnt[j]);
            lcnt[j] = 0;
        }
        __syncthreads();
        for (int e = base + t; e < e_end; e += 256) {
            int d = ei[NEDGE + e];
            int s = ei[e];
            int b = d >> BSHIFT;
            int off = atomicAdd(&lcnt[b], 1);
            int pos = lbase[b] + off;
            if (pos < BCAP)
                ebuf[(size_t)b * BCAP + pos] =
                    (unsigned)s | ((unsigned)(d & 127) << 16);
        }
        return;
    }

    // ---- h_ln tile ----
    bf16_t* Bs  = (bf16_t*)smem;
    bf16_t* Csw = (bf16_t*)(smem + 32768);
    const int tile = bid - bid / 5;
    const int r0 = tile * 64;
    const int lane = t & 63, wave = t >> 6, l15 = lane & 15, quad = lane >> 4;
    uint4 wr[8];
    bf16x8 af[4];
    floatx4 acc[8];
    float bias_r[8];
    for (int ni = 0; ni < 8; ++ni) bias_r[ni] = b_lin[ni * 16 + l15];

    {
        int gr = min(r0 + wave * 16 + l15, M - 1);
        const float* p = x + (size_t)gr * 128 + quad * 8;
        for (int kc = 0; kc < 4; ++kc) {
            float4 u0 = *(const float4*)(p + kc * 32);
            float4 u1 = *(const float4*)(p + kc * 32 + 4);
            bf16x8 f;
            f[0] = (bf16_t)u0.x; f[1] = (bf16_t)u0.y;
            f[2] = (bf16_t)u0.z; f[3] = (bf16_t)u0.w;
            f[4] = (bf16_t)u1.x; f[5] = (bf16_t)u1.y;
            f[6] = (bf16_t)u1.z; f[7] = (bf16_t)u1.w;
            af[kc] = f;
        }
    }
    load_w_regs(wt, wr, t);
    store_w_regs(wr, Bs, t);
    __syncthreads();
    kloop64(af, Bs, acc, l15, quad);
    write_Csw(Csw, acc, bias_r, lane, wave, 0);
    __syncthreads();

    int row = t >> 2, p4 = t & 3;
    int gr = r0 + row;
    uint4 raw[4];
    float vals[32];
    float s = 0.f, sq = 0.f;
    for (int i = 0; i < 4; ++i) {
        int lg = p4 * 4 + i;
        raw[i] = *(const uint4*)&Csw[row * 128 + ((lg ^ (row & 15)) * 8)];
        const unsigned* u = (const unsigned*)&raw[i];
        for (int k = 0; k < 4; ++k) {
            float f0 = bfbits2f(u[k] << 16);
            float f1 = bfbits2f(u[k] & 0xffff0000u);
            vals[i * 8 + k * 2] = f0; vals[i * 8 + k * 2 + 1] = f1;
            s += f0 + f1; sq += f0 * f0 + f1 * f1;
        }
    }
    s += __shfl_xor(s, 1, 64);  sq += __shfl_xor(sq, 1, 64);
    s += __shfl_xor(s, 2, 64);  sq += __shfl_xor(sq, 2, 64);
    float m   = s * (1.f / 128.f);
    float var = fmaxf(sq * (1.f / 128.f) - m * m, 0.f);
    float rs  = rsqrtf(var + 1e-5f);
    if (gr < M) {
        for (int i = 0; i < 4; ++i) {
            int lg = p4 * 4 + i;
            *(uint4*)(h + (size_t)gr * 128 + lg * 8) = raw[i];
            unsigned short ob[8];
            for (int k = 0; k < 8; ++k) {
                int col = lg * 8 + k;
                ob[k] = f2bfbits((vals[i * 8 + k] - m) * rs * ln_g[col] + ln_b[col]);
            }
            uint4 o;
            o.x = ob[0] | ((unsigned)ob[1] << 16);
            o.y = ob[2] | ((unsigned)ob[3] << 16);
            o.z = ob[4] | ((unsigned)ob[5] << 16);
            o.w = ob[6] | ((unsigned)ob[7] << 16);
            *(uint4*)(xres + (size_t)gr * 128 + lg * 8) = o;
        }
    }
}

// ---------------------------------------------------------------------------
// gather_agg: one block per 128-node bucket. agg accumulated in LDS fp32 via
// ds_add_f32 atomics. Column swizzle pos = (c&3)*32 + (c>>2): each atomic
// wave-instruction hits bank l31 -> conflict-free (2-way across halves=free).
// ---------------------------------------------------------------------------
__global__ __launch_bounds__(512, 4) void gather_agg(
    const int* __restrict__ gcur, const unsigned* __restrict__ ebuf,
    const bf16_t* __restrict__ h, bf16_t* __restrict__ agg, int M)
{
    __shared__ float acc[16384];          // 128 nodes x 128 cols, 64 KB
    const int t = threadIdx.x;
    {
        float4 z; z.x = 0.f; z.y = 0.f; z.z = 0.f; z.w = 0.f;
        for (int i = t; i < 4096; i += 512) *(float4*)&acc[i * 4] = z;
    }
    __syncthreads();
    const int b = blockIdx.x;
    const int total = min(gcur[b], BCAP);
    const unsigned* eb = ebuf + (size_t)b * BCAP;
    const int wave = t >> 6, lane = t & 63;
    const int half = lane >> 5, l31 = lane & 31;
    const unsigned short* hu = (const unsigned short*)h;

    unsigned pkc[4];
    const int base0 = wave * 8;
    #pragma unroll
    for (int k = 0; k < 4; ++k)
        pkc[k] = (total > 0) ? eb[min(base0 + 2 * k + half, total - 1)] : 0u;

    for (int base = base0; base < total; base += 64) {
        unsigned pk[4];
        #pragma unroll
        for (int k = 0; k < 4; ++k) pk[k] = pkc[k];
        ushort4 hr[4];
        #pragma unroll
        for (int k = 0; k < 4; ++k)
            hr[k] = *(const ushort4*)(hu + (size_t)(pk[k] & 0xFFFFu) * 128 + l31 * 4);
        int nb = base + 64;
        if (nb < total) {
            #pragma unroll
            for (int k = 0; k < 4; ++k)
                pkc[k] = eb[min(nb + 2 * k + half, total - 1)];
        }
        #pragma unroll
        for (int k = 0; k < 4; ++k) {
            if (base + 2 * k + half < total) {
                float* ap = acc + ((pk[k] >> 16) & 127) * 128 + l31;
                atomicAdd(ap,      bfbits2f((unsigned)hr[k].x << 16));
                atomicAdd(ap + 32, bfbits2f((unsigned)hr[k].y << 16));
                atomicAdd(ap + 64, bfbits2f((unsigned)hr[k].z << 16));
                atomicAdd(ap + 96, bfbits2f((unsigned)hr[k].w << 16));
            }
        }
    }
    __syncthreads();
    const int node0 = b << BSHIFT;
    for (int i = t; i < 2048; i += 512) {
        int row = i >> 4, g = i & 15;
        int gr = node0 + row;
        if (gr < M) {
            unsigned short ob[8];
            #pragma unroll
            for (int k = 0; k < 8; ++k) {
                int c = g * 8 + k;
                ob[k] = f2bfbits(acc[row * 128 + ((c & 3) << 5) + (c >> 2)]);
            }
            uint4 o;
            o.x = ob[0] | ((unsigned)ob[1] << 16);
            o.y = ob[2] | ((unsigned)ob[3] << 16);
            o.z = ob[4] | ((unsigned)ob[5] << 16);
            o.w = ob[6] | ((unsigned)ob[7] << 16);
            *(uint4*)(agg + (size_t)gr * 128 + g * 8) = o;
        }
    }
}

// ---------------------------------------------------------------------------
// mega: per 64-row tile: 3 branch MLPs (alpha/beta in regs, gamma in acc)
// -> y in-register -> gelu(y@Wf1+bf1)@Wf2+bf2 + xres -> out fp32.
// Zero intermediate global traffic.
// ---------------------------------------------------------------------------
__device__ __forceinline__ void two_layer(
    const bf16_t* __restrict__ wt, int w2i, int wni,
    const float* __restrict__ B1, const float* __restrict__ B2, int act1,
    const bf16x8 (&af_h)[4], bf16x8 (&af_t)[4],
    uint4 (&wr)[8], floatx4 (&acc)[8],
    float (&b1_r)[8], float (&b2_r)[8],
    bf16_t* Bs, bf16_t* Csw, int t, int lane, int wave, int l15, int quad)
{
    // pre: wr holds W_layer1 (Bs free). post: acc = act1(h@W1+b1)@W2 (pre-b2),
    // wr holds weight index wni.
    store_w_regs(wr, Bs, t);
    for (int ni = 0; ni < 8; ++ni) {
        b1_r[ni] = B1[ni * 16 + l15];
        b2_r[ni] = B2[ni * 16 + l15];
    }
    __syncthreads();
    kloop64(af_h, Bs, acc, l15, quad);
    load_w_regs(wt + w2i * 16384, wr, t);
    write_Csw(Csw, acc, b1_r, lane, wave, act1);
    __syncthreads();
    store_w_regs(wr, Bs, t);
    afrag_Csw(Csw, af_t, lane, wave);
    load_w_regs(wt + wni * 16384, wr, t);
    __syncthreads();
    kloop64(af_t, Bs, acc, l15, quad);
}

__global__ __launch_bounds__(256, 2) void mega(
    const bf16_t* __restrict__ h, const bf16_t* __restrict__ wt,
    const float* __restrict__ ba1, const float* __restrict__ ba2,
    const float* __restrict__ bb1, const float* __restrict__ bb2,
    const float* __restrict__ bg1, const float* __restrict__ bg2,
    const float* __restrict__ bf1, const float* __restrict__ bf2,
    const bf16_t* __restrict__ agg, const float* __restrict__ deg,
    const bf16_t* __restrict__ xres, float* __restrict__ out, int M)
{
    __shared__ __align__(16) char smem[49152];
    bf16_t* Bs  = (bf16_t*)smem;
    bf16_t* Csw = (bf16_t*)(smem + 32768);
    float*  Cf  = (float*)smem;                 // overlays Bs in epilogue
    const int t = threadIdx.x;
    const int r0 = blockIdx.x * 64;
    const int lane = t & 63, wave = t >> 6, l15 = lane & 15, quad = lane >> 4;
    uint4 wr[8];
    bf16x8 af_h[4], af_t[4];
    floatx4 acc[8];
    float b1_r[8], b2_r[8];
    float al_r[8][4], be_r[8][4];

    afrag_gbf16(h, af_h, r0, lane, wave, M);
    load_w_regs(wt + 1 * 16384, wr, t);         // Wa1

    // ---- alpha ----
    two_layer(wt, 2, 3, ba1, ba2, 1, af_h, af_t, wr, acc, b1_r, b2_r,
              Bs, Csw, t, lane, wave, l15, quad);
    #pragma unroll
    for (int ni = 0; ni < 8; ++ni)
        #pragma unroll
        for (int r = 0; r < 4; ++r)
            al_r[ni][r] = act_rt(acc[ni][r] + b2_r[ni], 3);
    __syncthreads();

    // ---- beta ----
    two_layer(wt, 4, 5, bb1, bb2, 1, af_h, af_t, wr, acc, b1_r, b2_r,
              Bs, Csw, t, lane, wave, l15, quad);
    #pragma unroll
    for (int ni = 0; ni < 8; ++ni)
        #pragma unroll
        for (int r = 0; r < 4; ++r)
            be_r[ni][r] = act_rt(acc[ni][r] + b2_r[ni], 3);
    __syncthreads();

    // ---- gamma (stays in acc; b2_r = bg2; wr ends holding Wf1) ----
    two_layer(wt, 6, 7, bg1, bg2, 2, af_h, af_t, wr, acc, b1_r, b2_r,
              Bs, Csw, t, lane, wave, l15, quad);

    // stage agg tile into Csw (linear layout); Csw free since afrag+sync in helper
    for (int i = 0; i < 4; ++i) {
        int c = t + i * 256;
        int row = c >> 4, g = c & 15;
        int gr = min(r0 + row, M - 1);
        *(uint4*)&Csw[row * 128 + g * 8] = *(const uint4*)(agg + (size_t)gr * 128 + g * 8);
    }
    float dg_r[4];
    #pragma unroll
    for (int r = 0; r < 4; ++r)
        dg_r[r] = deg[min(r0 + wave * 16 + quad * 4 + r, M - 1)];
    __syncthreads();                            // agg staged; all kloops done

    // ---- y = (beta*agg + gamma) / (alpha + beta*deg), in-register ----
    #pragma unroll
    for (int ni = 0; ni < 8; ++ni) {
        int col = ni * 16 + l15;
        #pragma unroll
        for (int r = 0; r < 4; ++r) {
            int row = wave * 16 + quad * 4 + r;
            float aggv = (float)Csw[row * 128 + col];
            float ga = acc[ni][r] + b2_r[ni];
            float alv = al_r[ni][r], bev = be_r[ni][r];
            acc[ni][r] = (bev * aggv + ga) / (alv + bev * dg_r[r]);
        }
    }
    __syncthreads();                            // all agg reads done

    // ---- final MLP: gelu(y@Wf1+bf1)@Wf2 + bf2 + xres ----
    store_w_regs(wr, Bs, t);                    // Bs <- Wf1
    {
        float zb[8] = {0.f, 0.f, 0.f, 0.f, 0.f, 0.f, 0.f, 0.f};
        write_Csw(Csw, acc, zb, lane, wave, 0); // Csw <- y (bf16)
    }
    load_w_regs(wt + 8 * 16384, wr, t);         // Wf2
    for (int ni = 0; ni < 8; ++ni) {
        b1_r[ni] = bf1[ni * 16 + l15];
        b2_r[ni] = bf2[ni * 16 + l15];
    }
    __syncthreads();
    afrag_Csw(Csw, af_t, lane, wave);
    kloop64(af_t, Bs, acc, l15, quad);
    __syncthreads();
    write_Csw(Csw, acc, b1_r, lane, wave, 2);   // gelu
    store_w_regs(wr, Bs, t);                    // Bs <- Wf2
    __syncthreads();
    afrag_Csw(Csw, af_t, lane, wave);
    kloop64(af_t, Bs, acc, l15, quad);
    __syncthreads();                            // Bs reads done -> Cf overlay safe

    #pragma unroll
    for (int ni = 0; ni < 8; ++ni) {
        int col = ni * 16 + l15;
        #pragma unroll
        for (int r = 0; r < 4; ++r) {
            int row = wave * 16 + quad * 4 + r;
            Cf[row * 128 + col] = acc[ni][r] + b2_r[ni];
        }
    }
    __syncthreads();
    for (int i = 0; i < 8; ++i) {
        int c = t + i * 256;
        int row = c >> 5, q = c & 31;
        int gr = r0 + row;
        if (gr < M) {
            float4 v = *(const float4*)&Cf[row * 128 + q * 4];
            uint2 xr = *(const uint2*)(xres + (size_t)gr * 128 + q * 4);
            v.x += bfbits2f(xr.x << 16);
            v.y += bfbits2f(xr.x & 0xffff0000u);
            v.z += bfbits2f(xr.y << 16);
            v.w += bfbits2f(xr.y & 0xffff0000u);
            *(float4*)(out + (size_t)gr * 128 + q * 4) = v;
        }
    }
}

// ---------------------------------------------------------------------------
extern "C" void kernel_launch(void* const* d_in, const int* in_sizes, int n_in,
                              void* d_out, int out_size, void* d_ws, size_t ws_size,
                              hipStream_t stream)
{
    const float* x    = (const float*)d_in[0];
    const int*   ei   = (const int*)d_in[1];
    const float* deg  = (const float*)d_in[2];
    const float* W_lin = (const float*)d_in[3];  const float* b_lin = (const float*)d_in[4];
    const float* Wa1 = (const float*)d_in[5];    const float* ba1 = (const float*)d_in[6];
    const float* Wa2 = (const float*)d_in[7];    const float* ba2 = (const float*)d_in[8];
    const float* Wb1 = (const float*)d_in[9];    const float* bb1 = (const float*)d_in[10];
    const float* Wb2 = (const float*)d_in[11];   const float* bb2 = (const float*)d_in[12];
    const float* Wg1 = (const float*)d_in[13];   const float* bg1 = (const float*)d_in[14];
    const float* Wg2 = (const float*)d_in[15];   const float* bg2 = (const float*)d_in[16];
    const float* Wf1 = (const float*)d_in[17];   const float* bf1 = (const float*)d_in[18];
    const float* Wf2 = (const float*)d_in[19];   const float* bf2 = (const float*)d_in[20];
    const float* ln_g = (const float*)d_in[21];  const float* ln_b = (const float*)d_in[22];

    const int M = NODES;
    const size_t NB2 = (size_t)M * 128 * 2;   // bf16 [N,128]

    char* ws = (char*)d_ws;
    size_t off = 0;
    bf16_t* wt   = (bf16_t*)(ws + off); off += (size_t)9 * 16384 * 2;
    bf16_t* h    = (bf16_t*)(ws + off); off += NB2;
    bf16_t* xres = (bf16_t*)(ws + off); off += NB2;
    bf16_t* agg  = (bf16_t*)(ws + off); off += NB2;
    int* gcur      = (int*)(ws + off); off += 512 * 4;
    unsigned* ebuf = (unsigned*)(ws + off); off += (size_t)NBUCK * BCAP * 4;
    float* outp = (float*)d_out;

    dim3 blk(256);

    // weights transpose + gcur zero
    prep_w_zero<<<10, blk, 0, stream>>>(
        W_lin, Wa1, Wa2, Wb1, Wb2, Wg1, Wg2, Wf1, Wf2, wt, gcur);

    // h/LN co-launched with pass-1 edge binning (782 tiles + 195 p1 blocks)
    hln_p1<<<NT_TILES + NP1, blk, 0, stream>>>(
        x, wt, b_lin, ln_g, ln_b, h, xres, ei, gcur, ebuf, M);

    // bucket-local LDS-atomic segment sum (replaces pass-2 CSR + gather)
    gather_agg<<<NBUCK, dim3(512), 0, stream>>>(gcur, ebuf, h, agg, M);

    // branches + y + final MLP + residual, all fused
    mega<<<NT_TILES, blk, 0, stream>>>(
        h, wt, ba1, ba2, bb1, bb2, bg1, bg2, bf1, bf2,
        agg, deg, xres, outp, M);
}

// Round 2
// 380.548 us; speedup vs baseline: 2.4815x; 2.4815x over previous
//
#include <hip/hip_runtime.h>
#include <hip/hip_bf16.h>
#include <math.h>

#define NODES 50000
#define NEDGE 800000
#define NT_TILES 782        // 64-row tiles
#define NECAP 64            // per-node edge slot capacity (Poisson(16): P(>64)~0)
#define NP1 195             // pass-1 blocks
#define EPB1 4104           // edges per pass-1 block (195*4104 >= 800000)

typedef __bf16 bf16_t;
typedef __bf16 bf16x8 __attribute__((ext_vector_type(8)));
typedef float floatx4 __attribute__((ext_vector_type(4)));

__device__ __forceinline__ float bfbits2f(unsigned int hi16) {
    union { unsigned int u; float f; } c; c.u = hi16; return c.f;
}
__device__ __forceinline__ unsigned short f2bfbits(float f) {
    bf16_t b = (bf16_t)f; unsigned short u;
    __builtin_memcpy(&u, &b, 2); return u;
}

// act: 0=none, 1=relu, 2=gelu(tanh-approx, fast exp), 3=softplus(fast)
__device__ __forceinline__ float act_rt(float v, int act) {
    if (act == 1) return fmaxf(v, 0.f);
    if (act == 2) {
        float w = 0.79788456f * (v + 0.044715f * v * v * v);
        float e = __expf(2.f * w);
        float th = 1.f - 2.f / (e + 1.f);
        return 0.5f * v * (1.f + th);
    }
    if (act == 3) return fmaxf(v, 0.f) + __logf(1.f + __expf(-fabsf(v)));
    return v;
}

// ---------------------------------------------------------------------------
// prep: blocks 0..8 transpose weights fp32->bf16; blocks 9..24 zero cnt
// ---------------------------------------------------------------------------
__global__ __launch_bounds__(256) void prep_w_zero(
    const float* __restrict__ w0, const float* __restrict__ w1,
    const float* __restrict__ w2, const float* __restrict__ w3,
    const float* __restrict__ w4, const float* __restrict__ w5,
    const float* __restrict__ w6, const float* __restrict__ w7,
    const float* __restrict__ w8, bf16_t* __restrict__ wt,
    int* __restrict__ cnt)
{
    if (blockIdx.x >= 9) {
        for (int idx = (blockIdx.x - 9) * 256 + threadIdx.x; idx < NODES;
             idx += 16 * 256)
            cnt[idx] = 0;
        return;
    }
    const float* Ws[9] = {w0, w1, w2, w3, w4, w5, w6, w7, w8};
    const float* W = Ws[blockIdx.x];
    bf16_t* o = wt + blockIdx.x * 16384;
    for (int idx = threadIdx.x; idx < 16384; idx += 256) {
        int k = idx >> 7, n = idx & 127;
        o[n * 128 + k] = (bf16_t)W[idx];
    }
}

// ---------------------------------------------------------------------------
// GEMM building blocks, 64-row tile structure.
// ---------------------------------------------------------------------------
__device__ __forceinline__ void load_w_regs(const bf16_t* __restrict__ W,
                                            uint4 (&wr)[8], int t)
{
    for (int i = 0; i < 8; ++i) {
        int c = t + i * 256;
        int row = c >> 4, g = c & 15;
        wr[i] = *(const uint4*)(W + row * 128 + g * 8);
    }
}
__device__ __forceinline__ void store_w_regs(const uint4 (&wr)[8],
                                             bf16_t* Bs, int t)
{
    for (int i = 0; i < 8; ++i) {
        int c = t + i * 256;
        int row = c >> 4, g = c & 15;
        *(uint4*)&Bs[row * 128 + ((g ^ (row & 15)) * 8)] = wr[i];
    }
}
__device__ __forceinline__ void afrag_gbf16(const bf16_t* __restrict__ A,
        bf16x8 (&af)[4], int r0, int lane, int wave, int M)
{
    int gr = r0 + wave * 16 + (lane & 15);
    gr = min(gr, M - 1);
    const bf16_t* p = A + (size_t)gr * 128 + (lane >> 4) * 8;
    for (int kc = 0; kc < 4; ++kc)
        af[kc] = *(const bf16x8*)(p + kc * 32);
}
__device__ __forceinline__ void kloop64(const bf16x8 (&af)[4], const bf16_t* Bs,
                                        floatx4 (&acc)[8], int l15, int quad)
{
    for (int ni = 0; ni < 8; ++ni)
        for (int r = 0; r < 4; ++r) acc[ni][r] = 0.f;
    for (int kc = 0; kc < 4; ++kc) {
        int kg = kc * 4 + quad;
        bf16x8 b[8];
        for (int ni = 0; ni < 8; ++ni) {
            int row = ni * 16 + l15;
            b[ni] = *(const bf16x8*)&Bs[row * 128 + ((kg ^ l15) * 8)];
        }
        for (int ni = 0; ni < 8; ++ni)
            acc[ni] = __builtin_amdgcn_mfma_f32_16x16x32_bf16(
                af[kc], b[ni], acc[ni], 0, 0, 0);
    }
}
__device__ __forceinline__ void write_Csw(bf16_t* Csw, floatx4 (&acc)[8],
        const float (&bias_r)[8], int lane, int wave, int act)
{
    const int l15 = lane & 15, quad = lane >> 4;
    for (int ni = 0; ni < 8; ++ni) {
        int col = ni * 16 + l15;
        for (int r = 0; r < 4; ++r) {
            int row = wave * 16 + quad * 4 + r;
            float v = act_rt(acc[ni][r] + bias_r[ni], act);
            Csw[row * 128 + (((col >> 3) ^ (row & 15)) << 3) + (col & 7)] = (bf16_t)v;
        }
    }
}
__device__ __forceinline__ void afrag_Csw(const bf16_t* Csw, bf16x8 (&af)[4],
                                          int lane, int wave)
{
    int l15 = lane & 15, quad = lane >> 4;
    int row = wave * 16 + l15;
    for (int kc = 0; kc < 4; ++kc) {
        int kg = kc * 4 + quad;
        af[kc] = *(const bf16x8*)&Csw[row * 128 + ((kg ^ l15) * 8)];
    }
}

// ---------------------------------------------------------------------------
// hln_p1: blocks with bid%5==4 run pass-1 direct per-node edge-slot fill
// (195 blocks); the rest run h_ln tiles (tile = bid - bid/5, 782 tiles).
// ---------------------------------------------------------------------------
__global__ __launch_bounds__(256, 3) void hln_p1(
    const float* __restrict__ x, const bf16_t* __restrict__ wt,
    const float* __restrict__ b_lin,
    const float* __restrict__ ln_g, const float* __restrict__ ln_b,
    bf16_t* __restrict__ h, bf16_t* __restrict__ xres,
    const int* __restrict__ ei, int* __restrict__ cnt,
    int* __restrict__ nodeE, int M)
{
    __shared__ __align__(16) char smem[49152];
    const int t = threadIdx.x;
    const int bid = blockIdx.x;

    if (bid % 5 == 4) {
        // ---- pass 1: scatter edges into per-node slots ----
        int p1id = bid / 5;
        int base = p1id * EPB1;
        int e_end = min(base + EPB1, NEDGE);
        for (int e = base + t; e < e_end; e += 256) {
            int d = ei[NEDGE + e];
            int s = ei[e];
            int slot = atomicAdd(&cnt[d], 1);
            if (slot < NECAP) nodeE[d * NECAP + slot] = s;
        }
        return;
    }

    // ---- h_ln tile ----
    bf16_t* Bs  = (bf16_t*)smem;
    bf16_t* Csw = (bf16_t*)(smem + 32768);
    const int tile = bid - bid / 5;
    const int r0 = tile * 64;
    const int lane = t & 63, wave = t >> 6, l15 = lane & 15, quad = lane >> 4;
    uint4 wr[8];
    bf16x8 af[4];
    floatx4 acc[8];
    float bias_r[8];
    for (int ni = 0; ni < 8; ++ni) bias_r[ni] = b_lin[ni * 16 + l15];

    {
        int gr = min(r0 + wave * 16 + l15, M - 1);
        const float* p = x + (size_t)gr * 128 + quad * 8;
        for (int kc = 0; kc < 4; ++kc) {
            float4 u0 = *(const float4*)(p + kc * 32);
            float4 u1 = *(const float4*)(p + kc * 32 + 4);
            bf16x8 f;
            f[0] = (bf16_t)u0.x; f[1] = (bf16_t)u0.y;
            f[2] = (bf16_t)u0.z; f[3] = (bf16_t)u0.w;
            f[4] = (bf16_t)u1.x; f[5] = (bf16_t)u1.y;
            f[6] = (bf16_t)u1.z; f[7] = (bf16_t)u1.w;
            af[kc] = f;
        }
    }
    load_w_regs(wt, wr, t);
    store_w_regs(wr, Bs, t);
    __syncthreads();
    kloop64(af, Bs, acc, l15, quad);
    write_Csw(Csw, acc, bias_r, lane, wave, 0);
    __syncthreads();

    int row = t >> 2, p4 = t & 3;
    int gr = r0 + row;
    uint4 raw[4];
    float vals[32];
    float s = 0.f, sq = 0.f;
    for (int i = 0; i < 4; ++i) {
        int lg = p4 * 4 + i;
        raw[i] = *(const uint4*)&Csw[row * 128 + ((lg ^ (row & 15)) * 8)];
        const unsigned* u = (const unsigned*)&raw[i];
        for (int k = 0; k < 4; ++k) {
            float f0 = bfbits2f(u[k] << 16);
            float f1 = bfbits2f(u[k] & 0xffff0000u);
            vals[i * 8 + k * 2] = f0; vals[i * 8 + k * 2 + 1] = f1;
            s += f0 + f1; sq += f0 * f0 + f1 * f1;
        }
    }
    s += __shfl_xor(s, 1, 64);  sq += __shfl_xor(sq, 1, 64);
    s += __shfl_xor(s, 2, 64);  sq += __shfl_xor(sq, 2, 64);
    float m   = s * (1.f / 128.f);
    float var = fmaxf(sq * (1.f / 128.f) - m * m, 0.f);
    float rs  = rsqrtf(var + 1e-5f);
    if (gr < M) {
        for (int i = 0; i < 4; ++i) {
            int lg = p4 * 4 + i;
            *(uint4*)(h + (size_t)gr * 128 + lg * 8) = raw[i];
            unsigned short ob[8];
            for (int k = 0; k < 8; ++k) {
                int col = lg * 8 + k;
                ob[k] = f2bfbits((vals[i * 8 + k] - m) * rs * ln_g[col] + ln_b[col]);
            }
            uint4 o;
            o.x = ob[0] | ((unsigned)ob[1] << 16);
            o.y = ob[2] | ((unsigned)ob[3] << 16);
            o.z = ob[4] | ((unsigned)ob[5] << 16);
            o.w = ob[6] | ((unsigned)ob[7] << 16);
            *(uint4*)(xres + (size_t)gr * 128 + lg * 8) = o;
        }
    }
}

// ---------------------------------------------------------------------------
// gather: one wave per node (proven-fast shape); quad-parallel 16B row loads,
// 2 edges in flight per quad; cross-quad shuffle reduce; write agg bf16.
// ---------------------------------------------------------------------------
__global__ __launch_bounds__(256) void gather_kernel(
    const int* __restrict__ cnt, const int* __restrict__ nodeE,
    const bf16_t* __restrict__ h, bf16_t* __restrict__ agg, int M)
{
    int wave = threadIdx.x >> 6, lane = threadIdx.x & 63;
    int node = blockIdx.x * 4 + wave;
    if (node >= M) return;
    int n = min(__builtin_amdgcn_readfirstlane(cnt[node]), NECAP);
    const int* ep = nodeE + (size_t)node * NECAP;
    int grp = lane >> 4, c16 = lane & 15;
    float a[8] = {0.f, 0.f, 0.f, 0.f, 0.f, 0.f, 0.f, 0.f};

    for (int j = 0; j < n; j += 8) {
        int e0 = j + grp, e1 = j + 4 + grp;
        int i0 = ep[min(e0, n - 1)];
        int i1 = ep[min(e1, n - 1)];
        uint4 v0 = *(const uint4*)(h + (size_t)i0 * 128 + c16 * 8);
        uint4 v1 = *(const uint4*)(h + (size_t)i1 * 128 + c16 * 8);
        if (e0 < n) {
            const unsigned* u = (const unsigned*)&v0;
            for (int k = 0; k < 4; ++k) {
                a[2 * k]     += bfbits2f(u[k] << 16);
                a[2 * k + 1] += bfbits2f(u[k] & 0xffff0000u);
            }
        }
        if (e1 < n) {
            const unsigned* u = (const unsigned*)&v1;
            for (int k = 0; k < 4; ++k) {
                a[2 * k]     += bfbits2f(u[k] << 16);
                a[2 * k + 1] += bfbits2f(u[k] & 0xffff0000u);
            }
        }
    }
    for (int k = 0; k < 8; ++k) {
        a[k] += __shfl_xor(a[k], 16, 64);
        a[k] += __shfl_xor(a[k], 32, 64);
    }
    if (lane < 16) {
        unsigned short o[8];
        for (int k = 0; k < 8; ++k) o[k] = f2bfbits(a[k]);
        uint4 ov;
        ov.x = o[0] | ((unsigned)o[1] << 16);
        ov.y = o[2] | ((unsigned)o[3] << 16);
        ov.z = o[4] | ((unsigned)o[5] << 16);
        ov.w = o[6] | ((unsigned)o[7] << 16);
        *(uint4*)(agg + (size_t)node * 128 + (size_t)c16 * 8) = ov;
    }
}

// ---------------------------------------------------------------------------
// mega: per 64-row tile: 3 branch MLPs (alpha/beta packed bf16 in regs,
// gamma in acc) -> y in-register -> gelu(y@Wf1+bf1)@Wf2+bf2 + xres -> out.
// ---------------------------------------------------------------------------
__device__ __forceinline__ void two_layer(
    const bf16_t* __restrict__ wt, int w2i, int wni,
    const float* __restrict__ B1, const float* __restrict__ B2, int act1,
    const bf16x8 (&af_h)[4], bf16x8 (&af_t)[4],
    uint4 (&wr)[8], floatx4 (&acc)[8],
    float (&b1_r)[8], float (&b2_r)[8],
    bf16_t* Bs, bf16_t* Csw, int t, int lane, int wave, int l15, int quad)
{
    // pre: wr holds W_layer1 (Bs free). post: acc = act1(h@W1+b1)@W2 (pre-b2),
    // wr holds weight index wni.
    store_w_regs(wr, Bs, t);
    for (int ni = 0; ni < 8; ++ni) {
        b1_r[ni] = B1[ni * 16 + l15];
        b2_r[ni] = B2[ni * 16 + l15];
    }
    __syncthreads();
    kloop64(af_h, Bs, acc, l15, quad);
    load_w_regs(wt + w2i * 16384, wr, t);
    write_Csw(Csw, acc, b1_r, lane, wave, act1);
    __syncthreads();
    store_w_regs(wr, Bs, t);
    afrag_Csw(Csw, af_t, lane, wave);
    load_w_regs(wt + wni * 16384, wr, t);
    __syncthreads();
    kloop64(af_t, Bs, acc, l15, quad);
}

__global__ __launch_bounds__(256, 3) void mega(
    const bf16_t* __restrict__ h, const bf16_t* __restrict__ wt,
    const float* __restrict__ ba1, const float* __restrict__ ba2,
    const float* __restrict__ bb1, const float* __restrict__ bb2,
    const float* __restrict__ bg1, const float* __restrict__ bg2,
    const float* __restrict__ bf1, const float* __restrict__ bf2,
    const bf16_t* __restrict__ agg, const float* __restrict__ deg,
    const bf16_t* __restrict__ xres, float* __restrict__ out, int M)
{
    __shared__ __align__(16) char smem[49152];
    bf16_t* Bs  = (bf16_t*)smem;
    bf16_t* Csw = (bf16_t*)(smem + 32768);
    float*  Cf  = (float*)smem;                 // overlays Bs in epilogue
    const int t = threadIdx.x;
    const int r0 = blockIdx.x * 64;
    const int lane = t & 63, wave = t >> 6, l15 = lane & 15, quad = lane >> 4;
    uint4 wr[8];
    bf16x8 af_h[4], af_t[4];
    floatx4 acc[8];
    float b1_r[8], b2_r[8];
    unsigned al_pk[8][2], be_pk[8][2];          // alpha/beta packed bf16 pairs

    afrag_gbf16(h, af_h, r0, lane, wave, M);
    load_w_regs(wt + 1 * 16384, wr, t);         // Wa1

    // ---- alpha ----
    two_layer(wt, 2, 3, ba1, ba2, 1, af_h, af_t, wr, acc, b1_r, b2_r,
              Bs, Csw, t, lane, wave, l15, quad);
    #pragma unroll
    for (int ni = 0; ni < 8; ++ni)
        #pragma unroll
        for (int j = 0; j < 2; ++j)
            al_pk[ni][j] =
                (unsigned)f2bfbits(act_rt(acc[ni][2 * j] + b2_r[ni], 3)) |
                ((unsigned)f2bfbits(act_rt(acc[ni][2 * j + 1] + b2_r[ni], 3)) << 16);
    __syncthreads();

    // ---- beta ----
    two_layer(wt, 4, 5, bb1, bb2, 1, af_h, af_t, wr, acc, b1_r, b2_r,
              Bs, Csw, t, lane, wave, l15, quad);
    #pragma unroll
    for (int ni = 0; ni < 8; ++ni)
        #pragma unroll
        for (int j = 0; j < 2; ++j)
            be_pk[ni][j] =
                (unsigned)f2bfbits(act_rt(acc[ni][2 * j] + b2_r[ni], 3)) |
                ((unsigned)f2bfbits(act_rt(acc[ni][2 * j + 1] + b2_r[ni], 3)) << 16);
    __syncthreads();

    // ---- gamma (stays in acc; b2_r = bg2; wr ends holding Wf1) ----
    two_layer(wt, 6, 7, bg1, bg2, 2, af_h, af_t, wr, acc, b1_r, b2_r,
              Bs, Csw, t, lane, wave, l15, quad);

    // stage agg tile into Csw (linear layout); Csw free since afrag+sync in helper
    for (int i = 0; i < 4; ++i) {
        int c = t + i * 256;
        int row = c >> 4, g = c & 15;
        int gr = min(r0 + row, M - 1);
        *(uint4*)&Csw[row * 128 + g * 8] = *(const uint4*)(agg + (size_t)gr * 128 + g * 8);
    }
    float dg_r[4];
    #pragma unroll
    for (int r = 0; r < 4; ++r)
        dg_r[r] = deg[min(r0 + wave * 16 + quad * 4 + r, M - 1)];
    __syncthreads();                            // agg staged; all kloops done

    // ---- y = (beta*agg + gamma) / (alpha + beta*deg), in-register ----
    #pragma unroll
    for (int ni = 0; ni < 8; ++ni) {
        int col = ni * 16 + l15;
        #pragma unroll
        for (int r = 0; r < 4; ++r) {
            int row = wave * 16 + quad * 4 + r;
            float aggv = (float)Csw[row * 128 + col];
            float ga = acc[ni][r] + b2_r[ni];
            unsigned ap = al_pk[ni][r >> 1], bp = be_pk[ni][r >> 1];
            float alv = bfbits2f((r & 1) ? (ap & 0xffff0000u) : (ap << 16));
            float bev = bfbits2f((r & 1) ? (bp & 0xffff0000u) : (bp << 16));
            acc[ni][r] = (bev * aggv + ga) / (alv + bev * dg_r[r]);
        }
    }
    __syncthreads();                            // all agg reads done

    // ---- final MLP: gelu(y@Wf1+bf1)@Wf2 + bf2 + xres ----
    store_w_regs(wr, Bs, t);                    // Bs <- Wf1
    {
        float zb[8] = {0.f, 0.f, 0.f, 0.f, 0.f, 0.f, 0.f, 0.f};
        write_Csw(Csw, acc, zb, lane, wave, 0); // Csw <- y (bf16)
    }
    load_w_regs(wt + 8 * 16384, wr, t);         // Wf2
    for (int ni = 0; ni < 8; ++ni) {
        b1_r[ni] = bf1[ni * 16 + l15];
        b2_r[ni] = bf2[ni * 16 + l15];
    }
    __syncthreads();
    afrag_Csw(Csw, af_t, lane, wave);
    kloop64(af_t, Bs, acc, l15, quad);
    __syncthreads();
    write_Csw(Csw, acc, b1_r, lane, wave, 2);   // gelu
    store_w_regs(wr, Bs, t);                    // Bs <- Wf2
    __syncthreads();
    afrag_Csw(Csw, af_t, lane, wave);
    kloop64(af_t, Bs, acc, l15, quad);
    __syncthreads();                            // Bs reads done -> Cf overlay safe

    #pragma unroll
    for (int ni = 0; ni < 8; ++ni) {
        int col = ni * 16 + l15;
        #pragma unroll
        for (int r = 0; r < 4; ++r) {
            int row = wave * 16 + quad * 4 + r;
            Cf[row * 128 + col] = acc[ni][r] + b2_r[ni];
        }
    }
    __syncthreads();
    for (int i = 0; i < 8; ++i) {
        int c = t + i * 256;
        int row = c >> 5, q = c & 31;
        int gr = r0 + row;
        if (gr < M) {
            float4 v = *(const float4*)&Cf[row * 128 + q * 4];
            uint2 xr = *(const uint2*)(xres + (size_t)gr * 128 + q * 4);
            v.x += bfbits2f(xr.x << 16);
            v.y += bfbits2f(xr.x & 0xffff0000u);
            v.z += bfbits2f(xr.y << 16);
            v.w += bfbits2f(xr.y & 0xffff0000u);
            *(float4*)(out + (size_t)gr * 128 + q * 4) = v;
        }
    }
}

// ---------------------------------------------------------------------------
extern "C" void kernel_launch(void* const* d_in, const int* in_sizes, int n_in,
                              void* d_out, int out_size, void* d_ws, size_t ws_size,
                              hipStream_t stream)
{
    const float* x    = (const float*)d_in[0];
    const int*   ei   = (const int*)d_in[1];
    const float* deg  = (const float*)d_in[2];
    const float* W_lin = (const float*)d_in[3];  const float* b_lin = (const float*)d_in[4];
    const float* Wa1 = (const float*)d_in[5];    const float* ba1 = (const float*)d_in[6];
    const float* Wa2 = (const float*)d_in[7];    const float* ba2 = (const float*)d_in[8];
    const float* Wb1 = (const float*)d_in[9];    const float* bb1 = (const float*)d_in[10];
    const float* Wb2 = (const float*)d_in[11];   const float* bb2 = (const float*)d_in[12];
    const float* Wg1 = (const float*)d_in[13];   const float* bg1 = (const float*)d_in[14];
    const float* Wg2 = (const float*)d_in[15];   const float* bg2 = (const float*)d_in[16];
    const float* Wf1 = (const float*)d_in[17];   const float* bf1 = (const float*)d_in[18];
    const float* Wf2 = (const float*)d_in[19];   const float* bf2 = (const float*)d_in[20];
    const float* ln_g = (const float*)d_in[21];  const float* ln_b = (const float*)d_in[22];

    const int M = NODES;
    const size_t NB2 = (size_t)M * 128 * 2;   // bf16 [N,128]

    char* ws = (char*)d_ws;
    size_t off = 0;
    bf16_t* wt   = (bf16_t*)(ws + off); off += (size_t)9 * 16384 * 2;
    bf16_t* h    = (bf16_t*)(ws + off); off += NB2;
    bf16_t* xres = (bf16_t*)(ws + off); off += NB2;
    bf16_t* agg  = (bf16_t*)(ws + off); off += NB2;
    int* cnt     = (int*)(ws + off); off += (size_t)NODES * 4 + 64;
    int* nodeE   = (int*)(ws + off); off += (size_t)NODES * NECAP * 4;
    float* outp = (float*)d_out;

    dim3 blk(256);

    // weights transpose + cnt zero
    prep_w_zero<<<25, blk, 0, stream>>>(
        W_lin, Wa1, Wa2, Wb1, Wb2, Wg1, Wg2, Wf1, Wf2, wt, cnt);

    // h/LN co-launched with pass-1 direct edge-slot scatter
    hln_p1<<<NT_TILES + NP1, blk, 0, stream>>>(
        x, wt, b_lin, ln_g, ln_b, h, xres, ei, cnt, nodeE, M);

    // one wave per node: gather h rows, write agg
    gather_kernel<<<(M + 3) / 4, blk, 0, stream>>>(cnt, nodeE, h, agg, M);

    // branches + y + final MLP + residual, all fused
    mega<<<NT_TILES, blk, 0, stream>>>(
        h, wt, ba1, ba2, bb1, bb2, bg1, bg2, bf1, bf2,
        agg, deg, xres, outp, M);
}